// Round 1
// baseline (1121.620 us; speedup 1.0000x reference)
//
#include <hip/hip_runtime.h>
#include <math.h>

#define B_    2
#define L_    2048
#define D_    768
#define K_    12
#define KQ_   6
#define M_    4
#define H_    64
#define ZC_   780      // MEM + K
#define NTOK_ 4096     // B*L
#define NC_   64       // scan chunks per batch
#define LC_   32       // chunk length (L/NC)

__device__ __forceinline__ float softplus_f(float x) {
  return (x > 20.f) ? x : log1pf(expf(x));
}

// ---------------------------------------------------------------------------
// Precompute theta / w_int tables (per k,h,m) and softplus(decay_slopes)
// ---------------------------------------------------------------------------
__global__ void precomp_kernel(const float* __restrict__ theta_d_raw,
                               const float* __restrict__ decay,
                               float* __restrict__ theta_tab,
                               float* __restrict__ w_tab,
                               float* __restrict__ slopes_sp) {
  int idx = blockIdx.x * 256 + threadIdx.x;   // (k*64+h) in [0,768)
  if (idx < K_) slopes_sp[idx] = softplus_f(decay[idx]);
  if (idx >= K_ * H_) return;
  float td[M_], ta[M_];
#pragma unroll
  for (int m = 0; m < M_; ++m) td[m] = softplus_f(theta_d_raw[idx * M_ + m]) + 1e-4f;
  ta[0] = td[0];
#pragma unroll
  for (int m = 1; m < M_; ++m) ta[m] = ta[m - 1] + td[m];
  float total = ta[M_ - 1];
  float rs = 2.999f / total;                  // (TH_MAX - TH_MIN) / total
#pragma unroll
  for (int m = 0; m < M_; ++m) theta_tab[idx * M_ + m] = 0.001f + ta[m] * rs;
  float d0 = (ta[1] - ta[0]) * rs;
  float d1 = (ta[2] - ta[1]) * rs;
  float d2 = (ta[3] - ta[2]) * rs;
  w_tab[idx * M_ + 0] = 0.5f * d0;
  w_tab[idx * M_ + 1] = 0.5f * (d0 + d1);
  w_tab[idx * M_ + 2] = 0.5f * (d1 + d2);
  w_tab[idx * M_ + 3] = 0.5f * d2;
}

// ---------------------------------------------------------------------------
// Generic f32 tiled GEMM: C[M x N] = A[M x K] @ B[K x N]
// BM=BN=64, BK=16, 256 threads, 4x4 per thread. M %64==0, K %16==0, N arbitrary.
// ---------------------------------------------------------------------------
__global__ void gemm64_kernel(const float* __restrict__ A,
                              const float* __restrict__ Bm,
                              float* __restrict__ C,
                              int Mdim, int Ndim, int Kdim) {
  __shared__ float As[16][68];
  __shared__ float Bs[16][64];
  const int bn0 = blockIdx.x * 64;
  const int bm0 = blockIdx.y * 64;
  const int tid = threadIdx.x;
  const int tr = tid / 16;   // 0..15
  const int tc = tid % 16;   // 0..15
  float acc[4][4] = {};
  for (int k0 = 0; k0 < Kdim; k0 += 16) {
    {
      int kc = tid % 16;
      int r0 = tid / 16;
#pragma unroll
      for (int i = 0; i < 4; ++i) {
        int r = r0 + i * 16;
        As[kc][r] = A[(size_t)(bm0 + r) * Kdim + k0 + kc];
      }
    }
    {
      int nc = tid % 64;
      int kr0 = tid / 64;
      int n = bn0 + nc;
#pragma unroll
      for (int i = 0; i < 4; ++i) {
        int kr = kr0 + i * 4;
        Bs[kr][nc] = (n < Ndim) ? Bm[(size_t)(k0 + kr) * Ndim + n] : 0.f;
      }
    }
    __syncthreads();
#pragma unroll
    for (int kk = 0; kk < 16; ++kk) {
      float a[4], b[4];
#pragma unroll
      for (int i = 0; i < 4; ++i) a[i] = As[kk][tr * 4 + i];
#pragma unroll
      for (int j = 0; j < 4; ++j) b[j] = Bs[kk][tc * 4 + j];
#pragma unroll
      for (int i = 0; i < 4; ++i)
#pragma unroll
        for (int j = 0; j < 4; ++j) acc[i][j] += a[i] * b[j];
    }
    __syncthreads();
  }
#pragma unroll
  for (int i = 0; i < 4; ++i) {
    int m = bm0 + tr * 4 + i;
#pragma unroll
    for (int j = 0; j < 4; ++j) {
      int n = bn0 + tc * 4 + j;
      if (n < Ndim) C[(size_t)m * Ndim + n] = acc[i][j];
    }
  }
}

// ---------------------------------------------------------------------------
// Depthwise causal conv (CK=4) along l, per channel
// ---------------------------------------------------------------------------
__global__ void conv_kernel(const float* __restrict__ z,
                            const float* __restrict__ ck,
                            float* __restrict__ zc) {
  size_t idx = (size_t)blockIdx.x * 256 + threadIdx.x;
  if (idx >= (size_t)NTOK_ * ZC_) return;
  int c = (int)(idx % ZC_);
  int t = (int)(idx / ZC_);
  int l = t % L_;
  float acc = 0.f;
#pragma unroll
  for (int w = 0; w < 4; ++w) {
    int lw = l - 3 + w;
    if (lw >= 0) acc += z[idx - (size_t)(3 - w) * ZC_] * ck[w * ZC_ + c];
  }
  zc[idx] = acc;
}

// ---------------------------------------------------------------------------
// Scan pass A: per-(b,k,chunk) partial sums of (den, num_re[256], num_im[256])
// thread = (h,m): m = tid&3, h = tid>>2
// ---------------------------------------------------------------------------
__global__ void pass_a_kernel(const float* __restrict__ zc,
                              const float* __restrict__ theta_tab,
                              const float* __restrict__ score_scale,
                              const float* __restrict__ tanh_scale,
                              const float* __restrict__ slopes_sp,
                              float* __restrict__ csums) {
  const int c = blockIdx.x, k = blockIdx.y, b = blockIdx.z;
  const int tid = threadIdx.x;
  const int m = tid & 3, h = tid >> 2;
  const float theta_v = theta_tab[(k * H_ + h) * M_ + m];
  const float ts = tanh_scale[k], ss = score_scale[k], slope = slopes_sp[k];
  float sre = 0.f, sim = 0.f, dacc = 0.f;
  for (int ll = 0; ll < LC_; ++ll) {
    int l = c * LC_ + ll;
    size_t t = (size_t)b * L_ + l;
    float kv = zc[t * ZC_ + k * H_ + h];
    float sraw = zc[t * ZC_ + 768 + k];
    float lp = fminf(fmaxf(ss * sraw, -20.f), 20.f);
    float pw = expf(lp - slope * (float)(L_ - 1 - l));
    float ph = tanhf(ts * kv) * theta_v;
    float kvp = kv * pw;
    sre += kvp * cosf(ph);
    sim += kvp * sinf(ph);
    dacc += pw;
  }
  size_t base = (((size_t)b * K_ + k) * NC_ + c) * 513;
  if (tid == 0) csums[base] = dacc;
  csums[base + 1 + h * 4 + m] = sre;
  csums[base + 1 + 256 + h * 4 + m] = sim;
}

// ---------------------------------------------------------------------------
// Scan pass B: exclusive prefix over chunks, per (b,k), per state component
// ---------------------------------------------------------------------------
__global__ void pass_b_kernel(const float* __restrict__ csums,
                              float* __restrict__ cpre) {
  int bk = blockIdx.x;            // b*K + k
  int comp = threadIdx.x;         // 576 threads, 513 used
  if (comp >= 513) return;
  float run = 0.f;
  size_t base = (size_t)bk * NC_ * 513 + comp;
  for (int c = 0; c < NC_; ++c) {
    cpre[base + (size_t)c * 513] = run;
    run += csums[base + (size_t)c * 513];
  }
}

// ---------------------------------------------------------------------------
// Scan pass C: replay chunk with carried state, contract with q over M,
// emit out_re/out_im (b,l,K,H)
// ---------------------------------------------------------------------------
__global__ void pass_c_kernel(const float* __restrict__ zc,
                              const float* __restrict__ q,
                              const float* __restrict__ theta_tab,
                              const float* __restrict__ w_tab,
                              const float* __restrict__ score_scale,
                              const float* __restrict__ tanh_scale,
                              const float* __restrict__ slopes_sp,
                              const float* __restrict__ cpre,
                              float* __restrict__ out_re,
                              float* __restrict__ out_im) {
  const int c = blockIdx.x, k = blockIdx.y, b = blockIdx.z;
  const int tid = threadIdx.x;
  const int m = tid & 3, h = tid >> 2;
  size_t base = (((size_t)b * K_ + k) * NC_ + c) * 513;
  float den = cpre[base];
  float sre = cpre[base + 1 + h * 4 + m];
  float sim = cpre[base + 1 + 256 + h * 4 + m];
  const float theta_v = theta_tab[(k * H_ + h) * M_ + m];
  const float w = w_tab[(k * H_ + h) * M_ + m];
  const float ts = tanh_scale[k], ss = score_scale[k], slope = slopes_sp[k];
  const int kq = k >> 1;   // NREP = 2
  for (int ll = 0; ll < LC_; ++ll) {
    int l = c * LC_ + ll;
    size_t t = (size_t)b * L_ + l;
    float kv = zc[t * ZC_ + k * H_ + h];
    float sraw = zc[t * ZC_ + 768 + k];
    float lp = fminf(fmaxf(ss * sraw, -20.f), 20.f);
    float pw = expf(lp - slope * (float)(L_ - 1 - l));
    float ph = tanhf(ts * kv) * theta_v;
    float kvp = kv * pw;
    sre += kvp * cosf(ph);
    sim += kvp * sinf(ph);
    den += pw;
    float inv = 1.f / fmaxf(den, 1e-4f);
    float s_re = sre * inv, s_im = sim * inv;
    size_t qb = t * 3072 + (size_t)(((kq * H_ + h) * M_ + m) * 2);
    float qr = q[qb], qi = q[qb + 1];
    float tr = (s_re * qr + s_im * qi) * w;
    float ti = (s_im * qr - s_re * qi) * w;
    tr += __shfl_xor(tr, 1); tr += __shfl_xor(tr, 2);
    ti += __shfl_xor(ti, 1); ti += __shfl_xor(ti, 2);
    if (m == 0) {
      out_re[t * (size_t)D_ + k * H_ + h] = tr;
      out_im[t * (size_t)D_ + k * H_ + h] = ti;
    }
  }
}

// ---------------------------------------------------------------------------
// Fused spectral GEMM + gate + highway + SiLU -> y (NTOK x 2304)
// Per block: 64 tokens x 64 val-cols (and paired gate-cols), one k.
// A[t, kk] (Kdim=320) = [out_re*ns*gate | out_im*ns*gate | lat*hs]
// ---------------------------------------------------------------------------
__global__ void spec_gemm_kernel(const float* __restrict__ out_re,
                                 const float* __restrict__ out_im,
                                 const float* __restrict__ lat,
                                 const float* __restrict__ gatelin,
                                 const float* __restrict__ gate_b,
                                 const float* __restrict__ ns,
                                 const float* __restrict__ W_re,
                                 const float* __restrict__ W_im,
                                 const float* __restrict__ skip_up,
                                 const float* __restrict__ hs,
                                 float* __restrict__ y) {
  __shared__ float As[16][68];
  __shared__ float Bv[16][64];
  __shared__ float Bg[16][64];
  __shared__ float grow[64];
  __shared__ float ns_s[64];
  const int k = blockIdx.z;
  const int t0 = blockIdx.y * 64;
  const int n0 = blockIdx.x * 64;     // val column within [0,192)
  const int tid = threadIdx.x;
  const float hsk = hs[k];
  if (tid < 64) {
    float gl = gatelin[(size_t)(t0 + tid) * K_ + k] + gate_b[k];
    grow[tid] = 1.f / (1.f + expf(-gl));
    ns_s[tid] = ns[k * H_ + tid];
  }
  __syncthreads();
  float accv[4][4] = {}, accg[4][4] = {};
  const int tr = tid / 16, tc = tid % 16;
  for (int k0 = 0; k0 < 320; k0 += 16) {
    {
      int kc = tid % 16;
      int r0 = tid / 16;
      int kk = k0 + kc;
#pragma unroll
      for (int i = 0; i < 4; ++i) {
        int r = r0 + i * 16;
        size_t t = (size_t)(t0 + r);
        float v;
        if (kk < 64)       v = out_re[t * D_ + k * H_ + kk] * ns_s[kk] * grow[r];
        else if (kk < 128) v = out_im[t * D_ + k * H_ + (kk - 64)] * ns_s[kk - 64] * grow[r];
        else               v = lat[t * 192 + (kk - 128)] * hsk;
        As[kc][r] = v;
      }
    }
    {
      int nc = tid % 64;
      int kr0 = tid / 64;
      int cv = n0 + nc;
      int cg = cv + 192;
#pragma unroll
      for (int i = 0; i < 4; ++i) {
        int kr = kr0 + i * 4;
        int kk = k0 + kr;
        float bv, bg;
        if (kk < 64) {
          size_t r = ((size_t)k * H_ + kk) * 384;
          bv = W_re[r + cv]; bg = W_re[r + cg];
        } else if (kk < 128) {
          size_t r = ((size_t)k * H_ + (kk - 64)) * 384;
          bv = W_im[r + cv]; bg = W_im[r + cg];
        } else {
          size_t r = (size_t)(kk - 128) * 4608 + (size_t)k * 384;
          bv = skip_up[r + cv]; bg = skip_up[r + cg];
        }
        Bv[kr][nc] = bv; Bg[kr][nc] = bg;
      }
    }
    __syncthreads();
#pragma unroll
    for (int kk = 0; kk < 16; ++kk) {
      float a[4], bv[4], bg[4];
#pragma unroll
      for (int i = 0; i < 4; ++i) a[i] = As[kk][tr * 4 + i];
#pragma unroll
      for (int j = 0; j < 4; ++j) { bv[j] = Bv[kk][tc * 4 + j]; bg[j] = Bg[kk][tc * 4 + j]; }
#pragma unroll
      for (int i = 0; i < 4; ++i)
#pragma unroll
        for (int j = 0; j < 4; ++j) { accv[i][j] += a[i] * bv[j]; accg[i][j] += a[i] * bg[j]; }
    }
    __syncthreads();
  }
#pragma unroll
  for (int i = 0; i < 4; ++i) {
    size_t t = (size_t)(t0 + tr * 4 + i);
#pragma unroll
    for (int j = 0; j < 4; ++j) {
      int n = n0 + tc * 4 + j;
      float g = accg[i][j];
      float s = g / (1.f + expf(-g));   // silu
      y[t * 2304 + k * 192 + n] = accv[i][j] * s;
    }
  }
}

// ---------------------------------------------------------------------------
extern "C" void kernel_launch(void* const* d_in, const int* in_sizes, int n_in,
                              void* d_out, int out_size, void* d_ws, size_t ws_size,
                              hipStream_t stream) {
  const float* x            = (const float*)d_in[0];
  const float* W_mem        = (const float*)d_in[1];
  const float* conv_k       = (const float*)d_in[2];
  const float* W_q          = (const float*)d_in[3];
  const float* theta_d_raw  = (const float*)d_in[4];
  const float* decay_slopes = (const float*)d_in[5];
  const float* score_scale  = (const float*)d_in[6];
  const float* tanh_scale   = (const float*)d_in[7];
  const float* W_re         = (const float*)d_in[8];
  const float* W_im         = (const float*)d_in[9];
  const float* norm_scale   = (const float*)d_in[10];
  const float* gate_W       = (const float*)d_in[11];
  const float* gate_b       = (const float*)d_in[12];
  const float* skip_down_W  = (const float*)d_in[13];
  const float* skip_up_W    = (const float*)d_in[14];
  const float* highway_scale= (const float*)d_in[15];
  const float* out_W        = (const float*)d_in[16];
  float* out = (float*)d_out;
  float* ws = (float*)d_ws;

  // workspace layout (floats)
  float* theta_tab = ws;                    // 3072
  float* w_tab     = theta_tab + 3072;      // 3072
  float* slopes_sp = w_tab + 3072;          // 16
  float* z_pre     = slopes_sp + 16;        // 4096*780
  float* zc        = z_pre + (size_t)NTOK_ * ZC_;
  float* q         = zc + (size_t)NTOK_ * ZC_;       // 4096*3072 (reused as y)
  float* gatelin   = q + (size_t)NTOK_ * 3072;       // 4096*12
  float* lat       = gatelin + (size_t)NTOK_ * K_;   // 4096*192
  float* csums     = lat + (size_t)NTOK_ * 192;      // 2*12*64*513
  float* cpre      = csums + (size_t)B_ * K_ * NC_ * 513;
  float* out_re    = cpre + (size_t)B_ * K_ * NC_ * 513;  // 4096*768
  float* out_im    = out_re + (size_t)NTOK_ * D_;
  float* y         = q;  // alias: q dead after pass C

  precomp_kernel<<<3, 256, 0, stream>>>(theta_d_raw, decay_slopes, theta_tab, w_tab, slopes_sp);

  // z_pre = x @ W_mem  (4096 x 780)
  gemm64_kernel<<<dim3((ZC_ + 63) / 64, NTOK_ / 64), 256, 0, stream>>>(x, W_mem, z_pre, NTOK_, ZC_, D_);
  // depthwise causal conv
  conv_kernel<<<(int)(((size_t)NTOK_ * ZC_ + 255) / 256), 256, 0, stream>>>(z_pre, conv_k, zc);
  // q = x @ W_q  (4096 x 3072)
  gemm64_kernel<<<dim3(3072 / 64, NTOK_ / 64), 256, 0, stream>>>(x, W_q, q, NTOK_, 3072, D_);
  // gatelin = x @ gate_W  (4096 x 12)
  gemm64_kernel<<<dim3(1, NTOK_ / 64), 256, 0, stream>>>(x, gate_W, gatelin, NTOK_, K_, D_);
  // lat = x @ skip_down_W  (4096 x 192)
  gemm64_kernel<<<dim3(192 / 64, NTOK_ / 64), 256, 0, stream>>>(x, skip_down_W, lat, NTOK_, 192, D_);

  // chunked scan
  pass_a_kernel<<<dim3(NC_, K_, B_), 256, 0, stream>>>(zc, theta_tab, score_scale, tanh_scale, slopes_sp, csums);
  pass_b_kernel<<<B_ * K_, 576, 0, stream>>>(csums, cpre);
  pass_c_kernel<<<dim3(NC_, K_, B_), 256, 0, stream>>>(zc, q, theta_tab, w_tab, score_scale, tanh_scale,
                                                       slopes_sp, cpre, out_re, out_im);

  // fused spectral + highway + silu -> y (4096 x 2304)
  spec_gemm_kernel<<<dim3(3, NTOK_ / 64, K_), 256, 0, stream>>>(out_re, out_im, lat, gatelin, gate_b,
                                                                norm_scale, W_re, W_im, skip_up_W,
                                                                highway_scale, y);
  // out = y @ out_W  (4096 x 768)
  gemm64_kernel<<<dim3(768 / 64, NTOK_ / 64), 256, 0, stream>>>(y, out_W, out, NTOK_, D_, 2304);
}

// Round 2
// 535.350 us; speedup vs baseline: 2.0951x; 2.0951x over previous
//
#include <hip/hip_runtime.h>
#include <math.h>

#define B_    2
#define L_    2048
#define D_    768
#define K_    12
#define KQ_   6
#define M_    4
#define H_    64
#define ZC_   780      // MEM + K
#define NTOK_ 4096     // B*L
#define NC_   64       // scan chunks per batch
#define LC_   32       // chunk length (L/NC)

typedef __attribute__((ext_vector_type(8))) _Float16 half8;
typedef __attribute__((ext_vector_type(4))) float f32x4;

__device__ __forceinline__ float softplus_f(float x) {
  return (x > 20.f) ? x : log1pf(expf(x));
}

// ---------------------------------------------------------------------------
// Precompute theta / w_int tables (per k,h,m) and softplus(decay_slopes)
// ---------------------------------------------------------------------------
__global__ void precomp_kernel(const float* __restrict__ theta_d_raw,
                               const float* __restrict__ decay,
                               float* __restrict__ theta_tab,
                               float* __restrict__ w_tab,
                               float* __restrict__ slopes_sp) {
  int idx = blockIdx.x * 256 + threadIdx.x;   // (k*64+h) in [0,768)
  if (idx < K_) slopes_sp[idx] = softplus_f(decay[idx]);
  if (idx >= K_ * H_) return;
  float td[M_], ta[M_];
#pragma unroll
  for (int m = 0; m < M_; ++m) td[m] = softplus_f(theta_d_raw[idx * M_ + m]) + 1e-4f;
  ta[0] = td[0];
#pragma unroll
  for (int m = 1; m < M_; ++m) ta[m] = ta[m - 1] + td[m];
  float total = ta[M_ - 1];
  float rs = 2.999f / total;                  // (TH_MAX - TH_MIN) / total
#pragma unroll
  for (int m = 0; m < M_; ++m) theta_tab[idx * M_ + m] = 0.001f + ta[m] * rs;
  float d0 = (ta[1] - ta[0]) * rs;
  float d1 = (ta[2] - ta[1]) * rs;
  float d2 = (ta[3] - ta[2]) * rs;
  w_tab[idx * M_ + 0] = 0.5f * d0;
  w_tab[idx * M_ + 1] = 0.5f * (d0 + d1);
  w_tab[idx * M_ + 2] = 0.5f * (d1 + d2);
  w_tab[idx * M_ + 3] = 0.5f * d2;
}

// ---------------------------------------------------------------------------
// f32 tiled GEMM (kept only for tiny gatelin = x @ gate_W, N=12)
// ---------------------------------------------------------------------------
__global__ void gemm64_kernel(const float* __restrict__ A,
                              const float* __restrict__ Bm,
                              float* __restrict__ C,
                              int Mdim, int Ndim, int Kdim) {
  __shared__ float As[16][68];
  __shared__ float Bs[16][64];
  const int bn0 = blockIdx.x * 64;
  const int bm0 = blockIdx.y * 64;
  const int tid = threadIdx.x;
  const int tr = tid / 16;
  const int tc = tid % 16;
  float acc[4][4] = {};
  for (int k0 = 0; k0 < Kdim; k0 += 16) {
    {
      int kc = tid % 16;
      int r0 = tid / 16;
#pragma unroll
      for (int i = 0; i < 4; ++i) {
        int r = r0 + i * 16;
        As[kc][r] = A[(size_t)(bm0 + r) * Kdim + k0 + kc];
      }
    }
    {
      int nc = tid % 64;
      int kr0 = tid / 64;
      int n = bn0 + nc;
#pragma unroll
      for (int i = 0; i < 4; ++i) {
        int kr = kr0 + i * 4;
        Bs[kr][nc] = (n < Ndim) ? Bm[(size_t)(k0 + kr) * Ndim + n] : 0.f;
      }
    }
    __syncthreads();
#pragma unroll
    for (int kk = 0; kk < 16; ++kk) {
      float a[4], b[4];
#pragma unroll
      for (int i = 0; i < 4; ++i) a[i] = As[kk][tr * 4 + i];
#pragma unroll
      for (int j = 0; j < 4; ++j) b[j] = Bs[kk][tc * 4 + j];
#pragma unroll
      for (int i = 0; i < 4; ++i)
#pragma unroll
        for (int j = 0; j < 4; ++j) acc[i][j] += a[i] * b[j];
    }
    __syncthreads();
  }
#pragma unroll
  for (int i = 0; i < 4; ++i) {
    int m = bm0 + tr * 4 + i;
#pragma unroll
    for (int j = 0; j < 4; ++j) {
      int n = bn0 + tc * 4 + j;
      if (n < Ndim) C[(size_t)m * Ndim + n] = acc[i][j];
    }
  }
}

// ---------------------------------------------------------------------------
// f32 -> fp16 hi/lo split (element-wise), for A operands (x)
// ---------------------------------------------------------------------------
__global__ void cvt_split_kernel(const float* __restrict__ src,
                                 _Float16* __restrict__ h,
                                 _Float16* __restrict__ l, int n) {
  int gid = blockIdx.x * 256 + threadIdx.x;
  if (gid >= n) return;
  float v = src[gid];
  _Float16 hi = (_Float16)v;
  h[gid] = hi;
  l[gid] = (_Float16)(v - (float)hi);
}

// ---------------------------------------------------------------------------
// Tiled transpose + fp16 convert (+optional lo) with padding.
// src: (R x Nact) row-major, row stride srstride, batch stride sKstride.
// dst: (Npad x R) "n-major", row stride dstride, col offset doff, batch dKstride.
// Rows n in [Nact, Npad) are written as 0.
// ---------------------------------------------------------------------------
__global__ void cvt_t_kernel(const float* __restrict__ src, long sKstride, int srstride,
                             _Float16* __restrict__ h, _Float16* __restrict__ l,
                             long dKstride, int dstride, int doff,
                             int R, int Nact, int write_lo) {
  __shared__ float tile[32][33];
  const int kz = blockIdx.z;
  const float* s = src + (size_t)kz * sKstride;
  _Float16* dh = h + (size_t)kz * dKstride;
  _Float16* dl = l ? (l + (size_t)kz * dKstride) : nullptr;
  const int kb = blockIdx.x * 32;   // src-row (K) base
  const int nb = blockIdx.y * 32;   // src-col (N) base
  const int tx = threadIdx.x & 31, ty = threadIdx.x >> 5;  // 32 x 8
  for (int i = ty; i < 32; i += 8) {
    int kk = kb + i, n = nb + tx;
    tile[i][tx] = (kk < R && n < Nact) ? s[(size_t)kk * srstride + n] : 0.f;
  }
  __syncthreads();
  for (int i = ty; i < 32; i += 8) {
    int n = nb + i, kk = kb + tx;
    if (kk < R) {
      float v = tile[tx][i];
      _Float16 hi = (_Float16)v;
      size_t di = (size_t)n * dstride + doff + kk;
      dh[di] = hi;
      if (write_lo) dl[di] = (_Float16)(v - (float)hi);
    }
  }
}

// ---------------------------------------------------------------------------
// MFMA fp16 GEMM: C[M x Nact] = A[M x Kd] @ B[Kd x N], B given pre-transposed
// as Bt[Npad x Kd]. 128x128 tile, BK=32, 256 threads (4 waves, 64x64 each).
// NTERMS=1: plain fp16.  NTERMS=3: split hi/lo (hh + hl + lh), ~f32 accuracy.
// ---------------------------------------------------------------------------
template <int NTERMS>
__global__ __launch_bounds__(256)
void mfma_gemm_kernel(const _Float16* __restrict__ Ah, const _Float16* __restrict__ Al,
                      const _Float16* __restrict__ Bh, const _Float16* __restrict__ Bl,
                      float* __restrict__ C,
                      int Kd, int Nact,
                      long strideA, long strideB, long strideC) {
  constexpr int NBUF = (NTERMS > 1) ? 2 : 1;
  __shared__ __align__(16) _Float16 sA[NBUF][128 * 32];
  __shared__ __align__(16) _Float16 sB[NBUF][128 * 32];
  const int kz = blockIdx.z;
  const _Float16* A0 = Ah + (size_t)kz * strideA;
  const _Float16* B0 = Bh + (size_t)kz * strideB;
  float* Cb = C + (size_t)kz * strideC;
  const int bm0 = blockIdx.y * 128;
  const int bn0 = blockIdx.x * 128;
  const int tid = threadIdx.x;
  const int wave = tid >> 6, lane = tid & 63;
  const int m16 = lane & 15, quad = lane >> 4;
  const int wr = (wave & 1) * 64, wc = (wave >> 1) * 64;

  f32x4 acc[4][4];
#pragma unroll
  for (int i = 0; i < 4; ++i)
#pragma unroll
    for (int j = 0; j < 4; ++j) acc[i][j] = (f32x4){0.f, 0.f, 0.f, 0.f};

  const int lin = tid * 8;          // staging: elems [lin, lin+8), rows 0..63; +2048 -> rows 64..127
  const int r0 = lin >> 5;          // 0..63
  const int c0 = lin & 31;

  for (int k0 = 0; k0 < Kd; k0 += 32) {
    {
      const _Float16* gA = A0 + (size_t)(bm0 + r0) * Kd + (k0 + c0);
      *(half8*)&sA[0][lin] = *(const half8*)gA;
      *(half8*)&sA[0][lin + 2048] = *(const half8*)(gA + (size_t)64 * Kd);
      const _Float16* gB = B0 + (size_t)(bn0 + r0) * Kd + (k0 + c0);
      *(half8*)&sB[0][lin] = *(const half8*)gB;
      *(half8*)&sB[0][lin + 2048] = *(const half8*)(gB + (size_t)64 * Kd);
      if constexpr (NTERMS > 1) {
        const _Float16* gA1 = Al + (size_t)kz * strideA + (size_t)(bm0 + r0) * Kd + (k0 + c0);
        *(half8*)&sA[1][lin] = *(const half8*)gA1;
        *(half8*)&sA[1][lin + 2048] = *(const half8*)(gA1 + (size_t)64 * Kd);
        const _Float16* gB1 = Bl + (size_t)kz * strideB + (size_t)(bn0 + r0) * Kd + (k0 + c0);
        *(half8*)&sB[1][lin] = *(const half8*)gB1;
        *(half8*)&sB[1][lin + 2048] = *(const half8*)(gB1 + (size_t)64 * Kd);
      }
    }
    __syncthreads();
    half8 a0[4], b0[4];
#pragma unroll
    for (int i = 0; i < 4; ++i)
      a0[i] = *(const half8*)&sA[0][(wr + i * 16 + m16) * 32 + quad * 8];
#pragma unroll
    for (int j = 0; j < 4; ++j)
      b0[j] = *(const half8*)&sB[0][(wc + j * 16 + m16) * 32 + quad * 8];
    if constexpr (NTERMS == 1) {
#pragma unroll
      for (int i = 0; i < 4; ++i)
#pragma unroll
        for (int j = 0; j < 4; ++j)
          acc[i][j] = __builtin_amdgcn_mfma_f32_16x16x32_f16(a0[i], b0[j], acc[i][j], 0, 0, 0);
    } else {
      half8 a1[4], b1[4];
#pragma unroll
      for (int i = 0; i < 4; ++i)
        a1[i] = *(const half8*)&sA[1][(wr + i * 16 + m16) * 32 + quad * 8];
#pragma unroll
      for (int j = 0; j < 4; ++j)
        b1[j] = *(const half8*)&sB[1][(wc + j * 16 + m16) * 32 + quad * 8];
#pragma unroll
      for (int i = 0; i < 4; ++i)
#pragma unroll
        for (int j = 0; j < 4; ++j) {
          acc[i][j] = __builtin_amdgcn_mfma_f32_16x16x32_f16(a0[i], b0[j], acc[i][j], 0, 0, 0);
          acc[i][j] = __builtin_amdgcn_mfma_f32_16x16x32_f16(a0[i], b1[j], acc[i][j], 0, 0, 0);
          acc[i][j] = __builtin_amdgcn_mfma_f32_16x16x32_f16(a1[i], b0[j], acc[i][j], 0, 0, 0);
        }
    }
    __syncthreads();
  }
  // epilogue: C/D layout col=lane&15, row=quad*4+reg
#pragma unroll
  for (int i = 0; i < 4; ++i) {
    const int row0 = bm0 + wr + i * 16 + quad * 4;
#pragma unroll
    for (int j = 0; j < 4; ++j) {
      const int col = bn0 + wc + j * 16 + m16;
      if (col < Nact) {
#pragma unroll
        for (int r = 0; r < 4; ++r)
          Cb[(size_t)(row0 + r) * Nact + col] = acc[i][j][r];
      }
    }
  }
}

// ---------------------------------------------------------------------------
// Depthwise causal conv (CK=4) along l, per channel
// ---------------------------------------------------------------------------
__global__ void conv_kernel(const float* __restrict__ z,
                            const float* __restrict__ ck,
                            float* __restrict__ zc) {
  size_t idx = (size_t)blockIdx.x * 256 + threadIdx.x;
  if (idx >= (size_t)NTOK_ * ZC_) return;
  int c = (int)(idx % ZC_);
  int t = (int)(idx / ZC_);
  int l = t % L_;
  float acc = 0.f;
#pragma unroll
  for (int w = 0; w < 4; ++w) {
    int lw = l - 3 + w;
    if (lw >= 0) acc += z[idx - (size_t)(3 - w) * ZC_] * ck[w * ZC_ + c];
  }
  zc[idx] = acc;
}

// ---------------------------------------------------------------------------
// Scan pass A: per-(b,k,chunk) partial sums of (den, num_re[256], num_im[256])
// ---------------------------------------------------------------------------
__global__ void pass_a_kernel(const float* __restrict__ zc,
                              const float* __restrict__ theta_tab,
                              const float* __restrict__ score_scale,
                              const float* __restrict__ tanh_scale,
                              const float* __restrict__ slopes_sp,
                              float* __restrict__ csums) {
  const int c = blockIdx.x, k = blockIdx.y, b = blockIdx.z;
  const int tid = threadIdx.x;
  const int m = tid & 3, h = tid >> 2;
  const float theta_v = theta_tab[(k * H_ + h) * M_ + m];
  const float ts = tanh_scale[k], ss = score_scale[k], slope = slopes_sp[k];
  float sre = 0.f, sim = 0.f, dacc = 0.f;
  for (int ll = 0; ll < LC_; ++ll) {
    int l = c * LC_ + ll;
    size_t t = (size_t)b * L_ + l;
    float kv = zc[t * ZC_ + k * H_ + h];
    float sraw = zc[t * ZC_ + 768 + k];
    float lp = fminf(fmaxf(ss * sraw, -20.f), 20.f);
    float pw = expf(lp - slope * (float)(L_ - 1 - l));
    float ph = tanhf(ts * kv) * theta_v;
    float kvp = kv * pw;
    sre += kvp * cosf(ph);
    sim += kvp * sinf(ph);
    dacc += pw;
  }
  size_t base = (((size_t)b * K_ + k) * NC_ + c) * 513;
  if (tid == 0) csums[base] = dacc;
  csums[base + 1 + h * 4 + m] = sre;
  csums[base + 1 + 256 + h * 4 + m] = sim;
}

// ---------------------------------------------------------------------------
// Scan pass B: exclusive prefix over chunks
// ---------------------------------------------------------------------------
__global__ void pass_b_kernel(const float* __restrict__ csums,
                              float* __restrict__ cpre) {
  int bk = blockIdx.x;
  int comp = threadIdx.x;
  if (comp >= 513) return;
  float run = 0.f;
  size_t base = (size_t)bk * NC_ * 513 + comp;
  for (int c = 0; c < NC_; ++c) {
    cpre[base + (size_t)c * 513] = run;
    run += csums[base + (size_t)c * 513];
  }
}

// ---------------------------------------------------------------------------
// Scan pass C: replay with carried state, contract with q over M
// ---------------------------------------------------------------------------
__global__ void pass_c_kernel(const float* __restrict__ zc,
                              const float* __restrict__ q,
                              const float* __restrict__ theta_tab,
                              const float* __restrict__ w_tab,
                              const float* __restrict__ score_scale,
                              const float* __restrict__ tanh_scale,
                              const float* __restrict__ slopes_sp,
                              const float* __restrict__ cpre,
                              float* __restrict__ out_re,
                              float* __restrict__ out_im) {
  const int c = blockIdx.x, k = blockIdx.y, b = blockIdx.z;
  const int tid = threadIdx.x;
  const int m = tid & 3, h = tid >> 2;
  size_t base = (((size_t)b * K_ + k) * NC_ + c) * 513;
  float den = cpre[base];
  float sre = cpre[base + 1 + h * 4 + m];
  float sim = cpre[base + 1 + 256 + h * 4 + m];
  const float theta_v = theta_tab[(k * H_ + h) * M_ + m];
  const float w = w_tab[(k * H_ + h) * M_ + m];
  const float ts = tanh_scale[k], ss = score_scale[k], slope = slopes_sp[k];
  const int kq = k >> 1;   // NREP = 2
  for (int ll = 0; ll < LC_; ++ll) {
    int l = c * LC_ + ll;
    size_t t = (size_t)b * L_ + l;
    float kv = zc[t * ZC_ + k * H_ + h];
    float sraw = zc[t * ZC_ + 768 + k];
    float lp = fminf(fmaxf(ss * sraw, -20.f), 20.f);
    float pw = expf(lp - slope * (float)(L_ - 1 - l));
    float ph = tanhf(ts * kv) * theta_v;
    float kvp = kv * pw;
    sre += kvp * cosf(ph);
    sim += kvp * sinf(ph);
    den += pw;
    float inv = 1.f / fmaxf(den, 1e-4f);
    float s_re = sre * inv, s_im = sim * inv;
    size_t qb = t * 3072 + (size_t)(((kq * H_ + h) * M_ + m) * 2);
    float qr = q[qb], qi = q[qb + 1];
    float tr = (s_re * qr + s_im * qi) * w;
    float ti = (s_im * qr - s_re * qi) * w;
    tr += __shfl_xor(tr, 1); tr += __shfl_xor(tr, 2);
    ti += __shfl_xor(ti, 1); ti += __shfl_xor(ti, 2);
    if (m == 0) {
      out_re[t * (size_t)D_ + k * H_ + h] = tr;
      out_im[t * (size_t)D_ + k * H_ + h] = ti;
    }
  }
}

// ---------------------------------------------------------------------------
// Build spec-GEMM A operand (fp16): [k][t][320] =
//   [ out_re*ns*gate | out_im*ns*gate | lat*hs ]
// ---------------------------------------------------------------------------
__global__ void aspec_kernel(const float* __restrict__ out_re,
                             const float* __restrict__ out_im,
                             const float* __restrict__ lat,
                             const float* __restrict__ gatelin,
                             const float* __restrict__ gate_b,
                             const float* __restrict__ ns,
                             const float* __restrict__ hs,
                             _Float16* __restrict__ ah) {
  int gid = blockIdx.x * 256 + threadIdx.x;
  if (gid >= K_ * NTOK_ * 320) return;
  int kk = gid % 320;
  int r = gid / 320;
  int t = r % NTOK_;
  int k = r / NTOK_;
  float v;
  if (kk < 128) {
    float g = 1.f / (1.f + expf(-(gatelin[(size_t)t * K_ + k] + gate_b[k])));
    int h = kk & 63;
    const float* src = (kk < 64) ? out_re : out_im;
    v = src[(size_t)t * D_ + k * H_ + h] * ns[k * H_ + h] * g;
  } else {
    v = lat[(size_t)t * 192 + (kk - 128)] * hs[k];
  }
  ah[gid] = (_Float16)v;
}

// ---------------------------------------------------------------------------
// val/gate silu epilogue: yfull[k][t][384] -> y_h[t][2304] (fp16)
// ---------------------------------------------------------------------------
__global__ void silu_kernel(const float* __restrict__ yfull,
                            _Float16* __restrict__ yh) {
  int gid = blockIdx.x * 256 + threadIdx.x;
  if (gid >= K_ * NTOK_ * 192) return;
  int n = gid % 192;
  int r = gid / 192;
  int t = r % NTOK_;
  int k = r / NTOK_;
  size_t base = ((size_t)k * NTOK_ + t) * 384 + n;
  float val = yfull[base];
  float g = yfull[base + 192];
  float s = g / (1.f + expf(-g));
  yh[(size_t)t * 2304 + k * 192 + n] = (_Float16)(val * s);
}

// ---------------------------------------------------------------------------
extern "C" void kernel_launch(void* const* d_in, const int* in_sizes, int n_in,
                              void* d_out, int out_size, void* d_ws, size_t ws_size,
                              hipStream_t stream) {
  const float* x            = (const float*)d_in[0];
  const float* W_mem        = (const float*)d_in[1];
  const float* conv_k       = (const float*)d_in[2];
  const float* W_q          = (const float*)d_in[3];
  const float* theta_d_raw  = (const float*)d_in[4];
  const float* decay_slopes = (const float*)d_in[5];
  const float* score_scale  = (const float*)d_in[6];
  const float* tanh_scale   = (const float*)d_in[7];
  const float* W_re         = (const float*)d_in[8];
  const float* W_im         = (const float*)d_in[9];
  const float* norm_scale   = (const float*)d_in[10];
  const float* gate_W       = (const float*)d_in[11];
  const float* gate_b       = (const float*)d_in[12];
  const float* skip_down_W  = (const float*)d_in[13];
  const float* skip_up_W    = (const float*)d_in[14];
  const float* highway_scale= (const float*)d_in[15];
  const float* out_W        = (const float*)d_in[16];
  float* out = (float*)d_out;
  float* ws = (float*)d_ws;

  // ---- f32 region ----
  float* theta_tab = ws;                                  // 3072
  float* w_tab     = theta_tab + 3072;                    // 3072
  float* slopes_sp = w_tab + 3072;                        // 16
  float* z_pre     = slopes_sp + 16;                      // 3,194,880
  float* zc        = z_pre + (size_t)NTOK_ * ZC_;         // 3,194,880
  float* q         = zc + (size_t)NTOK_ * ZC_;            // 12,582,912
  float* gatelin   = q + (size_t)NTOK_ * 3072;            // 49,152
  float* lat       = gatelin + (size_t)NTOK_ * K_;        // 786,432
  float* csums     = lat + (size_t)NTOK_ * 192;           // 787,968
  float* cpre      = csums + (size_t)B_ * K_ * NC_ * 513; // 787,968
  float* out_re    = cpre + (size_t)B_ * K_ * NC_ * 513;  // 3,145,728
  float* out_im    = out_re + (size_t)NTOK_ * D_;         // 3,145,728
  float* f32_end   = out_im + (size_t)NTOK_ * D_;

  // aliases (lifetimes checked):
  float* yfull = z_pre;                 // 18,874,368 <= z_pre+zc+q (18,972,672)
  _Float16* y_h = (_Float16*)out_re;    // 9.4M fp16 <= out_re+out_im

  // ---- fp16 region ----
  _Float16* fp = (_Float16*)f32_end;
  _Float16* x_h    = fp;                fp += (size_t)NTOK_ * D_;
  _Float16* x_l    = fp;                fp += (size_t)NTOK_ * D_;
  _Float16* wmem_h = fp;                fp += (size_t)896 * 768;
  _Float16* wmem_l = fp;                fp += (size_t)896 * 768;
  _Float16* wq_h   = fp;                fp += (size_t)3072 * 768;
  _Float16* skd_h  = fp;                fp += (size_t)256 * 768;
  _Float16* outw_h = fp;                fp += (size_t)768 * 2304;
  _Float16* asp_h  = fp;                fp += (size_t)K_ * NTOK_ * 320;
  _Float16* bsp_h  = fp;                fp += (size_t)K_ * 384 * 320;

  precomp_kernel<<<3, 256, 0, stream>>>(theta_d_raw, decay_slopes, theta_tab, w_tab, slopes_sp);

  // conversions
  cvt_split_kernel<<<(NTOK_ * D_ + 255) / 256, 256, 0, stream>>>(x, x_h, x_l, NTOK_ * D_);
  // W_mem (768x780) -> wmem_t (896x768) hi+lo
  cvt_t_kernel<<<dim3(24, 28, 1), 256, 0, stream>>>(W_mem, 0, ZC_, wmem_h, wmem_l, 0, 768, 0, 768, ZC_, 1);
  // W_q (768x3072) -> (3072x768) hi
  cvt_t_kernel<<<dim3(24, 96, 1), 256, 0, stream>>>(W_q, 0, 3072, wq_h, nullptr, 0, 768, 0, 768, 3072, 0);
  // skip_down (768x192) -> (256x768) hi
  cvt_t_kernel<<<dim3(24, 8, 1), 256, 0, stream>>>(skip_down_W, 0, 192, skd_h, nullptr, 0, 768, 0, 768, 192, 0);
  // out_W (2304x768) -> (768x2304) hi
  cvt_t_kernel<<<dim3(72, 24, 1), 256, 0, stream>>>(out_W, 0, 768, outw_h, nullptr, 0, 2304, 0, 2304, 768, 0);
  // spec B: W_re (k,64,384) -> bsp[k][n][0:64]
  cvt_t_kernel<<<dim3(2, 12, K_), 256, 0, stream>>>(W_re, 64L * 384, 384, bsp_h, nullptr, 384L * 320, 320, 0, 64, 384, 0);
  // spec B: W_im -> bsp[k][n][64:128]
  cvt_t_kernel<<<dim3(2, 12, K_), 256, 0, stream>>>(W_im, 64L * 384, 384, bsp_h, nullptr, 384L * 320, 320, 64, 64, 384, 0);
  // spec B: skip_up (192,4608) slice k*384 -> bsp[k][n][128:320]
  cvt_t_kernel<<<dim3(6, 12, K_), 256, 0, stream>>>(skip_up_W, 384, 4608, bsp_h, nullptr, 384L * 320, 320, 128, 192, 384, 0);

  // z_pre = x @ W_mem  (split fp16, ~f32 accuracy for the nonlinear scan path)
  mfma_gemm_kernel<3><<<dim3(7, 32, 1), 256, 0, stream>>>(x_h, x_l, wmem_h, wmem_l, z_pre, 768, ZC_, 0, 0, 0);
  conv_kernel<<<(int)(((size_t)NTOK_ * ZC_ + 255) / 256), 256, 0, stream>>>(z_pre, conv_k, zc);
  // q = x @ W_q
  mfma_gemm_kernel<1><<<dim3(24, 32, 1), 256, 0, stream>>>(x_h, x_h, wq_h, wq_h, q, 768, 3072, 0, 0, 0);
  // gatelin = x @ gate_W (tiny, f32)
  gemm64_kernel<<<dim3(1, NTOK_ / 64), 256, 0, stream>>>(x, gate_W, gatelin, NTOK_, K_, D_);
  // lat = x @ skip_down_W
  mfma_gemm_kernel<1><<<dim3(2, 32, 1), 256, 0, stream>>>(x_h, x_h, skd_h, skd_h, lat, 768, 192, 0, 0, 0);

  // chunked scan (f32, unchanged)
  pass_a_kernel<<<dim3(NC_, K_, B_), 256, 0, stream>>>(zc, theta_tab, score_scale, tanh_scale, slopes_sp, csums);
  pass_b_kernel<<<B_ * K_, 576, 0, stream>>>(csums, cpre);
  pass_c_kernel<<<dim3(NC_, K_, B_), 256, 0, stream>>>(zc, q, theta_tab, w_tab, score_scale, tanh_scale,
                                                       slopes_sp, cpre, out_re, out_im);

  // spec A build (fp16) then batched spec GEMM -> yfull[k][t][384]
  aspec_kernel<<<(K_ * NTOK_ * 320 + 255) / 256, 256, 0, stream>>>(out_re, out_im, lat, gatelin, gate_b,
                                                                   norm_scale, highway_scale, asp_h);
  mfma_gemm_kernel<1><<<dim3(3, 32, K_), 256, 0, stream>>>(asp_h, asp_h, bsp_h, bsp_h, yfull, 320, 384,
                                                           (long)NTOK_ * 320, 384L * 320, (long)NTOK_ * 384);
  // silu epilogue -> y_h (fp16, 4096x2304)
  silu_kernel<<<(K_ * NTOK_ * 192 + 255) / 256, 256, 0, stream>>>(yfull, y_h);
  // out = y @ out_W
  mfma_gemm_kernel<1><<<dim3(6, 32, 1), 256, 0, stream>>>(y_h, y_h, outw_h, outw_h, out, 2304, 768, 0, 0, 0);
}

// Round 3
// 460.880 us; speedup vs baseline: 2.4337x; 1.1616x over previous
//
#include <hip/hip_runtime.h>
#include <math.h>

#define B_    2
#define L_    2048
#define D_    768
#define K_    12
#define KQ_   6
#define M_    4
#define H_    64
#define ZC_   780      // MEM + K
#define NTOK_ 4096     // B*L
#define NC_   64       // scan chunks per batch
#define LC_   32       // chunk length (L/NC)
#define QLN_  3264     // q (3072) + lat (192) fused N
#define QLP_  3328     // padded to 26*128

typedef __attribute__((ext_vector_type(8))) _Float16 half8;
typedef __attribute__((ext_vector_type(4))) float f32x4;

__device__ __forceinline__ float softplus_f(float x) {
  return (x > 20.f) ? x : log1pf(expf(x));
}

// async global->LDS 16B per lane (dest must be wave-uniform base + lane*16)
__device__ __forceinline__ void async16(const _Float16* g, _Float16* l) {
  __builtin_amdgcn_global_load_lds(
      (const __attribute__((address_space(1))) unsigned int*)g,
      (__attribute__((address_space(3))) unsigned int*)l, 16, 0, 0);
}

// ---------------------------------------------------------------------------
// Precompute theta / w_int tables (per k,h,m) and softplus(decay_slopes)
// ---------------------------------------------------------------------------
__global__ void precomp_kernel(const float* __restrict__ theta_d_raw,
                               const float* __restrict__ decay,
                               float* __restrict__ theta_tab,
                               float* __restrict__ w_tab,
                               float* __restrict__ slopes_sp) {
  int idx = blockIdx.x * 256 + threadIdx.x;   // (k*64+h) in [0,768)
  if (idx < K_) slopes_sp[idx] = softplus_f(decay[idx]);
  if (idx >= K_ * H_) return;
  float td[M_], ta[M_];
#pragma unroll
  for (int m = 0; m < M_; ++m) td[m] = softplus_f(theta_d_raw[idx * M_ + m]) + 1e-4f;
  ta[0] = td[0];
#pragma unroll
  for (int m = 1; m < M_; ++m) ta[m] = ta[m - 1] + td[m];
  float total = ta[M_ - 1];
  float rs = 2.999f / total;                  // (TH_MAX - TH_MIN) / total
#pragma unroll
  for (int m = 0; m < M_; ++m) theta_tab[idx * M_ + m] = 0.001f + ta[m] * rs;
  float d0 = (ta[1] - ta[0]) * rs;
  float d1 = (ta[2] - ta[1]) * rs;
  float d2 = (ta[3] - ta[2]) * rs;
  w_tab[idx * M_ + 0] = 0.5f * d0;
  w_tab[idx * M_ + 1] = 0.5f * (d0 + d1);
  w_tab[idx * M_ + 2] = 0.5f * (d1 + d2);
  w_tab[idx * M_ + 3] = 0.5f * d2;
}

// ---------------------------------------------------------------------------
// gatelin = x @ gate_W  (768x12).  One wave per token, gate_W in LDS.
// ---------------------------------------------------------------------------
__global__ __launch_bounds__(256) void gate_kernel(const float* __restrict__ x,
                                                   const float* __restrict__ gW,
                                                   float* __restrict__ gatelin) {
  __shared__ float gws[768 * 12];
  for (int i = threadIdx.x; i < 768 * 12; i += 256) gws[i] = gW[i];
  __syncthreads();
  const int wave = threadIdx.x >> 6, lane = threadIdx.x & 63;
  const int t = blockIdx.x * 4 + wave;
  const float* xt = x + (size_t)t * D_;
  float acc[12];
#pragma unroll
  for (int k = 0; k < 12; ++k) acc[k] = 0.f;
#pragma unroll
  for (int i = 0; i < 12; ++i) {
    float xv = xt[lane + 64 * i];
    const float* w = &gws[(lane + 64 * i) * 12];
#pragma unroll
    for (int k = 0; k < 12; ++k) acc[k] += xv * w[k];
  }
#pragma unroll
  for (int k = 0; k < 12; ++k) {
    acc[k] += __shfl_xor(acc[k], 32);
    acc[k] += __shfl_xor(acc[k], 16);
    acc[k] += __shfl_xor(acc[k], 8);
    acc[k] += __shfl_xor(acc[k], 4);
    acc[k] += __shfl_xor(acc[k], 2);
    acc[k] += __shfl_xor(acc[k], 1);
  }
  if (lane < 12) {
    float v = 0.f;
#pragma unroll
    for (int k = 0; k < 12; ++k)
      if (lane == k) v = acc[k];
    gatelin[(size_t)t * K_ + lane] = v;
  }
}

// ---------------------------------------------------------------------------
// f32 -> fp16 hi/lo split (element-wise), for A operands (x)
// ---------------------------------------------------------------------------
__global__ void cvt_split_kernel(const float* __restrict__ src,
                                 _Float16* __restrict__ h,
                                 _Float16* __restrict__ l, int n) {
  int gid = blockIdx.x * 256 + threadIdx.x;
  if (gid >= n) return;
  float v = src[gid];
  _Float16 hi = (_Float16)v;
  h[gid] = hi;
  l[gid] = (_Float16)(v - (float)hi);
}

// ---------------------------------------------------------------------------
// Tiled transpose + fp16 convert (+optional lo) with padding.
// ---------------------------------------------------------------------------
__global__ void cvt_t_kernel(const float* __restrict__ src, long sKstride, int srstride,
                             _Float16* __restrict__ h, _Float16* __restrict__ l,
                             long dKstride, int dstride, int doff,
                             int R, int Nact, int write_lo) {
  __shared__ float tile[32][33];
  const int kz = blockIdx.z;
  const float* s = src + (size_t)kz * sKstride;
  _Float16* dh = h + (size_t)kz * dKstride;
  _Float16* dl = l ? (l + (size_t)kz * dKstride) : nullptr;
  const int kb = blockIdx.x * 32;   // src-row (K) base
  const int nb = blockIdx.y * 32;   // src-col (N) base
  const int tx = threadIdx.x & 31, ty = threadIdx.x >> 5;  // 32 x 8
  for (int i = ty; i < 32; i += 8) {
    int kk = kb + i, n = nb + tx;
    tile[i][tx] = (kk < R && n < Nact) ? s[(size_t)kk * srstride + n] : 0.f;
  }
  __syncthreads();
  for (int i = ty; i < 32; i += 8) {
    int n = nb + i, kk = kb + tx;
    if (kk < R) {
      float v = tile[tx][i];
      _Float16 hi = (_Float16)v;
      size_t di = (size_t)n * dstride + doff + kk;
      dh[di] = hi;
      if (write_lo) dl[di] = (_Float16)(v - (float)hi);
    }
  }
}

// ---------------------------------------------------------------------------
// MFMA fp16 GEMM with async global->LDS staging.
// C[M x Nact] = A[M x Kd] @ Bt[Npad x Kd]^T. 128x128 tile, BK=32, 4 waves.
// NTERMS=1: plain fp16.  NTERMS=3: split hi/lo (hh + hl + lh).
// ---------------------------------------------------------------------------
template <int NTERMS>
__global__ __launch_bounds__(256)
void mfma_gemm_kernel(const _Float16* __restrict__ Ah, const _Float16* __restrict__ Al,
                      const _Float16* __restrict__ Bh, const _Float16* __restrict__ Bl,
                      float* __restrict__ C,
                      int Kd, int Nact,
                      long strideA, long strideB, long strideC) {
  constexpr int NBUF = (NTERMS > 1) ? 2 : 1;
  __shared__ __align__(16) _Float16 sA[NBUF][128 * 32];
  __shared__ __align__(16) _Float16 sB[NBUF][128 * 32];
  const int kz = blockIdx.z;
  const _Float16* A0 = Ah + (size_t)kz * strideA;
  const _Float16* B0 = Bh + (size_t)kz * strideB;
  float* Cb = C + (size_t)kz * strideC;
  const int bm0 = blockIdx.y * 128;
  const int bn0 = blockIdx.x * 128;
  const int tid = threadIdx.x;
  const int wave = tid >> 6, lane = tid & 63;
  const int m16 = lane & 15, quad = lane >> 4;
  const int wr = (wave & 1) * 64, wc = (wave >> 1) * 64;

  f32x4 acc[4][4];
#pragma unroll
  for (int i = 0; i < 4; ++i)
#pragma unroll
    for (int j = 0; j < 4; ++j) acc[i][j] = (f32x4){0.f, 0.f, 0.f, 0.f};

  const int lin = tid * 8;          // per-thread 8 halfs (16 B); block covers 2048 elems
  const int r0 = lin >> 5;          // 0..63
  const int c0 = lin & 31;

  for (int k0 = 0; k0 < Kd; k0 += 32) {
    {
      const _Float16* gA = A0 + (size_t)(bm0 + r0) * Kd + (k0 + c0);
      async16(gA, &sA[0][lin]);
      async16(gA + (size_t)64 * Kd, &sA[0][lin + 2048]);
      const _Float16* gB = B0 + (size_t)(bn0 + r0) * Kd + (k0 + c0);
      async16(gB, &sB[0][lin]);
      async16(gB + (size_t)64 * Kd, &sB[0][lin + 2048]);
      if constexpr (NTERMS > 1) {
        const _Float16* gA1 = Al + (size_t)kz * strideA + (size_t)(bm0 + r0) * Kd + (k0 + c0);
        async16(gA1, &sA[1][lin]);
        async16(gA1 + (size_t)64 * Kd, &sA[1][lin + 2048]);
        const _Float16* gB1 = Bl + (size_t)kz * strideB + (size_t)(bn0 + r0) * Kd + (k0 + c0);
        async16(gB1, &sB[1][lin]);
        async16(gB1 + (size_t)64 * Kd, &sB[1][lin + 2048]);
      }
    }
    __syncthreads();
    half8 a0[4], b0[4];
#pragma unroll
    for (int i = 0; i < 4; ++i)
      a0[i] = *(const half8*)&sA[0][(wr + i * 16 + m16) * 32 + quad * 8];
#pragma unroll
    for (int j = 0; j < 4; ++j)
      b0[j] = *(const half8*)&sB[0][(wc + j * 16 + m16) * 32 + quad * 8];
    if constexpr (NTERMS == 1) {
#pragma unroll
      for (int i = 0; i < 4; ++i)
#pragma unroll
        for (int j = 0; j < 4; ++j)
          acc[i][j] = __builtin_amdgcn_mfma_f32_16x16x32_f16(a0[i], b0[j], acc[i][j], 0, 0, 0);
    } else {
      half8 a1[4], b1[4];
#pragma unroll
      for (int i = 0; i < 4; ++i)
        a1[i] = *(const half8*)&sA[1][(wr + i * 16 + m16) * 32 + quad * 8];
#pragma unroll
      for (int j = 0; j < 4; ++j)
        b1[j] = *(const half8*)&sB[1][(wc + j * 16 + m16) * 32 + quad * 8];
#pragma unroll
      for (int i = 0; i < 4; ++i)
#pragma unroll
        for (int j = 0; j < 4; ++j) {
          acc[i][j] = __builtin_amdgcn_mfma_f32_16x16x32_f16(a0[i], b0[j], acc[i][j], 0, 0, 0);
          acc[i][j] = __builtin_amdgcn_mfma_f32_16x16x32_f16(a0[i], b1[j], acc[i][j], 0, 0, 0);
          acc[i][j] = __builtin_amdgcn_mfma_f32_16x16x32_f16(a1[i], b0[j], acc[i][j], 0, 0, 0);
        }
    }
    __syncthreads();
  }
  // epilogue: C/D layout col=lane&15, row=quad*4+reg
#pragma unroll
  for (int i = 0; i < 4; ++i) {
    const int row0 = bm0 + wr + i * 16 + quad * 4;
#pragma unroll
    for (int j = 0; j < 4; ++j) {
      const int col = bn0 + wc + j * 16 + m16;
      if (col < Nact) {
#pragma unroll
        for (int r = 0; r < 4; ++r)
          Cb[(size_t)(row0 + r) * Nact + col] = acc[i][j][r];
      }
    }
  }
}

// ---------------------------------------------------------------------------
// Depthwise causal conv (CK=4) along l, per channel
// ---------------------------------------------------------------------------
__global__ void conv_kernel(const float* __restrict__ z,
                            const float* __restrict__ ck,
                            float* __restrict__ zc) {
  size_t idx = (size_t)blockIdx.x * 256 + threadIdx.x;
  if (idx >= (size_t)NTOK_ * ZC_) return;
  int c = (int)(idx % ZC_);
  int t = (int)(idx / ZC_);
  int l = t % L_;
  float acc = 0.f;
#pragma unroll
  for (int w = 0; w < 4; ++w) {
    int lw = l - 3 + w;
    if (lw >= 0) acc += z[idx - (size_t)(3 - w) * ZC_] * ck[w * ZC_ + c];
  }
  zc[idx] = acc;
}

// ---------------------------------------------------------------------------
// Scan pass A: per-(b,k,chunk) partial sums of (den, num_re[256], num_im[256])
// ---------------------------------------------------------------------------
__global__ void pass_a_kernel(const float* __restrict__ zc,
                              const float* __restrict__ theta_tab,
                              const float* __restrict__ score_scale,
                              const float* __restrict__ tanh_scale,
                              const float* __restrict__ slopes_sp,
                              float* __restrict__ csums) {
  const int c = blockIdx.x, k = blockIdx.y, b = blockIdx.z;
  const int tid = threadIdx.x;
  const int m = tid & 3, h = tid >> 2;
  const float theta_v = theta_tab[(k * H_ + h) * M_ + m];
  const float ts = tanh_scale[k], ss = score_scale[k], slope = slopes_sp[k];
  float sre = 0.f, sim = 0.f, dacc = 0.f;
  for (int ll = 0; ll < LC_; ++ll) {
    int l = c * LC_ + ll;
    size_t t = (size_t)b * L_ + l;
    float kv = zc[t * ZC_ + k * H_ + h];
    float sraw = zc[t * ZC_ + 768 + k];
    float lp = fminf(fmaxf(ss * sraw, -20.f), 20.f);
    float pw = expf(lp - slope * (float)(L_ - 1 - l));
    float ph = tanhf(ts * kv) * theta_v;
    float kvp = kv * pw;
    sre += kvp * cosf(ph);
    sim += kvp * sinf(ph);
    dacc += pw;
  }
  size_t base = (((size_t)b * K_ + k) * NC_ + c) * 513;
  if (tid == 0) csums[base] = dacc;
  csums[base + 1 + h * 4 + m] = sre;
  csums[base + 1 + 256 + h * 4 + m] = sim;
}

// ---------------------------------------------------------------------------
// Scan pass B: exclusive prefix over chunks (parallel across components)
// ---------------------------------------------------------------------------
__global__ void pass_b_kernel(const float* __restrict__ csums,
                              float* __restrict__ cpre) {
  int bk = blockIdx.y;
  int comp = blockIdx.x * 64 + threadIdx.x;
  if (comp >= 513) return;
  float run = 0.f;
  size_t base = (size_t)bk * NC_ * 513 + comp;
  for (int c = 0; c < NC_; ++c) {
    cpre[base + (size_t)c * 513] = run;
    run += csums[base + (size_t)c * 513];
  }
}

// ---------------------------------------------------------------------------
// Scan pass C: replay with carried state, contract with q over M
// ---------------------------------------------------------------------------
__global__ void pass_c_kernel(const float* __restrict__ zc,
                              const float* __restrict__ qlat,
                              const float* __restrict__ theta_tab,
                              const float* __restrict__ w_tab,
                              const float* __restrict__ score_scale,
                              const float* __restrict__ tanh_scale,
                              const float* __restrict__ slopes_sp,
                              const float* __restrict__ cpre,
                              float* __restrict__ out_re,
                              float* __restrict__ out_im) {
  const int c = blockIdx.x, k = blockIdx.y, b = blockIdx.z;
  const int tid = threadIdx.x;
  const int m = tid & 3, h = tid >> 2;
  size_t base = (((size_t)b * K_ + k) * NC_ + c) * 513;
  float den = cpre[base];
  float sre = cpre[base + 1 + h * 4 + m];
  float sim = cpre[base + 1 + 256 + h * 4 + m];
  const float theta_v = theta_tab[(k * H_ + h) * M_ + m];
  const float w = w_tab[(k * H_ + h) * M_ + m];
  const float ts = tanh_scale[k], ss = score_scale[k], slope = slopes_sp[k];
  const int kq = k >> 1;   // NREP = 2
  for (int ll = 0; ll < LC_; ++ll) {
    int l = c * LC_ + ll;
    size_t t = (size_t)b * L_ + l;
    float kv = zc[t * ZC_ + k * H_ + h];
    float sraw = zc[t * ZC_ + 768 + k];
    float lp = fminf(fmaxf(ss * sraw, -20.f), 20.f);
    float pw = expf(lp - slope * (float)(L_ - 1 - l));
    float ph = tanhf(ts * kv) * theta_v;
    float kvp = kv * pw;
    sre += kvp * cosf(ph);
    sim += kvp * sinf(ph);
    den += pw;
    float inv = 1.f / fmaxf(den, 1e-4f);
    float s_re = sre * inv, s_im = sim * inv;
    size_t qb = t * QLN_ + (size_t)(((kq * H_ + h) * M_ + m) * 2);
    float qr = qlat[qb], qi = qlat[qb + 1];
    float tr = (s_re * qr + s_im * qi) * w;
    float ti = (s_im * qr - s_re * qi) * w;
    tr += __shfl_xor(tr, 1); tr += __shfl_xor(tr, 2);
    ti += __shfl_xor(ti, 1); ti += __shfl_xor(ti, 2);
    if (m == 0) {
      out_re[t * (size_t)D_ + k * H_ + h] = tr;
      out_im[t * (size_t)D_ + k * H_ + h] = ti;
    }
  }
}

// ---------------------------------------------------------------------------
// Build spec-GEMM A operand (fp16): [k][t][320] =
//   [ out_re*ns*gate | out_im*ns*gate | lat*hs ]   (lat = qlat cols 3072+)
// ---------------------------------------------------------------------------
__global__ void aspec_kernel(const float* __restrict__ out_re,
                             const float* __restrict__ out_im,
                             const float* __restrict__ qlat,
                             const float* __restrict__ gatelin,
                             const float* __restrict__ gate_b,
                             const float* __restrict__ ns,
                             const float* __restrict__ hs,
                             _Float16* __restrict__ ah) {
  int gid = blockIdx.x * 256 + threadIdx.x;
  if (gid >= K_ * NTOK_ * 320) return;
  int kk = gid % 320;
  int r = gid / 320;
  int t = r % NTOK_;
  int k = r / NTOK_;
  float v;
  if (kk < 128) {
    float g = 1.f / (1.f + expf(-(gatelin[(size_t)t * K_ + k] + gate_b[k])));
    int h = kk & 63;
    const float* src = (kk < 64) ? out_re : out_im;
    v = src[(size_t)t * D_ + k * H_ + h] * ns[k * H_ + h] * g;
  } else {
    v = qlat[(size_t)t * QLN_ + 3072 + (kk - 128)] * hs[k];
  }
  ah[gid] = (_Float16)v;
}

// ---------------------------------------------------------------------------
// val/gate silu epilogue: yfull[k][t][384] -> y_h[t][2304] (fp16)
// ---------------------------------------------------------------------------
__global__ void silu_kernel(const float* __restrict__ yfull,
                            _Float16* __restrict__ yh) {
  int gid = blockIdx.x * 256 + threadIdx.x;
  if (gid >= K_ * NTOK_ * 192) return;
  int n = gid % 192;
  int r = gid / 192;
  int t = r % NTOK_;
  int k = r / NTOK_;
  size_t base = ((size_t)k * NTOK_ + t) * 384 + n;
  float val = yfull[base];
  float g = yfull[base + 192];
  float s = g / (1.f + expf(-g));
  yh[(size_t)t * 2304 + k * 192 + n] = (_Float16)(val * s);
}

// ---------------------------------------------------------------------------
extern "C" void kernel_launch(void* const* d_in, const int* in_sizes, int n_in,
                              void* d_out, int out_size, void* d_ws, size_t ws_size,
                              hipStream_t stream) {
  const float* x            = (const float*)d_in[0];
  const float* W_mem        = (const float*)d_in[1];
  const float* conv_k       = (const float*)d_in[2];
  const float* W_q          = (const float*)d_in[3];
  const float* theta_d_raw  = (const float*)d_in[4];
  const float* decay_slopes = (const float*)d_in[5];
  const float* score_scale  = (const float*)d_in[6];
  const float* tanh_scale   = (const float*)d_in[7];
  const float* W_re         = (const float*)d_in[8];
  const float* W_im         = (const float*)d_in[9];
  const float* norm_scale   = (const float*)d_in[10];
  const float* gate_W       = (const float*)d_in[11];
  const float* gate_b       = (const float*)d_in[12];
  const float* skip_down_W  = (const float*)d_in[13];
  const float* skip_up_W    = (const float*)d_in[14];
  const float* highway_scale= (const float*)d_in[15];
  const float* out_W        = (const float*)d_in[16];
  float* out = (float*)d_out;
  float* ws = (float*)d_ws;

  // ---- f32 region ----
  float* theta_tab = ws;                                  // 3072
  float* w_tab     = theta_tab + 3072;                    // 3072
  float* slopes_sp = w_tab + 3072;                        // 16
  float* z_pre     = slopes_sp + 16;                      // 3,194,880
  float* zc        = z_pre + (size_t)NTOK_ * ZC_;         // 3,194,880
  float* qlat      = zc + (size_t)NTOK_ * ZC_;            // 4096*3264 = 13,369,344
  float* gatelin   = qlat + (size_t)NTOK_ * QLN_;         // 49,152
  float* csums     = gatelin + (size_t)NTOK_ * K_;        // 787,968
  float* cpre      = csums + (size_t)B_ * K_ * NC_ * 513; // 787,968
  float* out_re    = cpre + (size_t)B_ * K_ * NC_ * 513;  // 3,145,728
  float* out_im    = out_re + (size_t)NTOK_ * D_;         // 3,145,728
  float* f32_end   = out_im + (size_t)NTOK_ * D_;

  // aliases (lifetimes checked):
  float* yfull = z_pre;                 // 18,874,368 <= z_pre+zc+qlat (19,759,104)
  _Float16* y_h = (_Float16*)out_re;    // 9.4M fp16 <= out_re+out_im

  // ---- fp16 region ----
  _Float16* fp = (_Float16*)f32_end;
  _Float16* x_h    = fp;                fp += (size_t)NTOK_ * D_;
  _Float16* x_l    = fp;                fp += (size_t)NTOK_ * D_;
  _Float16* wmem_h = fp;                fp += (size_t)896 * 768;
  _Float16* wmem_l = fp;                fp += (size_t)896 * 768;
  _Float16* qlb_h  = fp;                fp += (size_t)QLP_ * 768;   // [W_q^T | skd^T | 0pad]
  _Float16* outw_h = fp;                fp += (size_t)768 * 2304;
  _Float16* asp_h  = fp;                fp += (size_t)K_ * NTOK_ * 320;
  _Float16* bsp_h  = fp;                fp += (size_t)K_ * 384 * 320;

  precomp_kernel<<<3, 256, 0, stream>>>(theta_d_raw, decay_slopes, theta_tab, w_tab, slopes_sp);

  // conversions
  cvt_split_kernel<<<(NTOK_ * D_ + 255) / 256, 256, 0, stream>>>(x, x_h, x_l, NTOK_ * D_);
  // W_mem (768x780) -> wmem_t (896x768) hi+lo
  cvt_t_kernel<<<dim3(24, 28, 1), 256, 0, stream>>>(W_mem, 0, ZC_, wmem_h, wmem_l, 0, 768, 0, 768, ZC_, 1);
  // W_q (768x3072) -> qlb rows [0,3072)
  cvt_t_kernel<<<dim3(24, 96, 1), 256, 0, stream>>>(W_q, 0, 3072, qlb_h, nullptr, 0, 768, 0, 768, 3072, 0);
  // skip_down (768x192) -> qlb rows [3072,3328) (rows >=3264 zeroed)
  cvt_t_kernel<<<dim3(24, 8, 1), 256, 0, stream>>>(skip_down_W, 0, 192, qlb_h + (size_t)3072 * 768, nullptr, 0, 768, 0, 768, 192, 0);
  // out_W (2304x768) -> (768x2304)
  cvt_t_kernel<<<dim3(72, 24, 1), 256, 0, stream>>>(out_W, 0, 768, outw_h, nullptr, 0, 2304, 0, 2304, 768, 0);
  // spec B: W_re (k,64,384) -> bsp[k][n][0:64]
  cvt_t_kernel<<<dim3(2, 12, K_), 256, 0, stream>>>(W_re, 64L * 384, 384, bsp_h, nullptr, 384L * 320, 320, 0, 64, 384, 0);
  // spec B: W_im -> bsp[k][n][64:128]
  cvt_t_kernel<<<dim3(2, 12, K_), 256, 0, stream>>>(W_im, 64L * 384, 384, bsp_h, nullptr, 384L * 320, 320, 64, 64, 384, 0);
  // spec B: skip_up (192,4608) slice k*384 -> bsp[k][n][128:320]
  cvt_t_kernel<<<dim3(6, 12, K_), 256, 0, stream>>>(skip_up_W, 384, 4608, bsp_h, nullptr, 384L * 320, 320, 128, 192, 384, 0);

  // z_pre = x @ W_mem  (split fp16, ~f32 accuracy for the nonlinear scan path)
  mfma_gemm_kernel<3><<<dim3(7, 32, 1), 256, 0, stream>>>(x_h, x_l, wmem_h, wmem_l, z_pre, 768, ZC_, 0, 0, 0);
  conv_kernel<<<(int)(((size_t)NTOK_ * ZC_ + 255) / 256), 256, 0, stream>>>(z_pre, conv_k, zc);
  // qlat = x @ [W_q | skip_down]  (4096 x 3264)
  mfma_gemm_kernel<1><<<dim3(26, 32, 1), 256, 0, stream>>>(x_h, x_h, qlb_h, qlb_h, qlat, 768, QLN_, 0, 0, 0);
  // gatelin = x @ gate_W (dedicated dot kernel)
  gate_kernel<<<NTOK_ / 4, 256, 0, stream>>>(x, gate_W, gatelin);

  // chunked scan (f32)
  pass_a_kernel<<<dim3(NC_, K_, B_), 256, 0, stream>>>(zc, theta_tab, score_scale, tanh_scale, slopes_sp, csums);
  pass_b_kernel<<<dim3(9, B_ * K_), 64, 0, stream>>>(csums, cpre);
  pass_c_kernel<<<dim3(NC_, K_, B_), 256, 0, stream>>>(zc, qlat, theta_tab, w_tab, score_scale, tanh_scale,
                                                       slopes_sp, cpre, out_re, out_im);

  // spec A build (fp16) then batched spec GEMM -> yfull[k][t][384]
  aspec_kernel<<<(K_ * NTOK_ * 320 + 255) / 256, 256, 0, stream>>>(out_re, out_im, qlat, gatelin, gate_b,
                                                                   norm_scale, highway_scale, asp_h);
  mfma_gemm_kernel<1><<<dim3(3, 32, K_), 256, 0, stream>>>(asp_h, asp_h, bsp_h, bsp_h, yfull, 320, 384,
                                                           (long)NTOK_ * 320, 384L * 320, (long)NTOK_ * 384);
  // silu epilogue -> y_h (fp16, 4096x2304)
  silu_kernel<<<(K_ * NTOK_ * 192 + 255) / 256, 256, 0, stream>>>(yfull, y_h);
  // out = y @ out_W
  mfma_gemm_kernel<1><<<dim3(6, 32, 1), 256, 0, stream>>>(y_h, y_h, outw_h, outw_h, out, 2304, 768, 0, 0, 0);
}